// Round 19
// baseline (293.499 us; speedup 1.0000x reference)
//
#include <hip/hip_runtime.h>
#include <hip/hip_bf16.h>
#include <math.h>

#define NNODES 20000
#define NEDGES 320000
#define ETOT   (NEDGES + NNODES)
#define SLOPE  0.2f
#define MAXDEG 96
#define LOG2E  1.44269504088896f

typedef __attribute__((ext_vector_type(8))) short bf16x8;
typedef __attribute__((ext_vector_type(4))) float f32x4;
typedef __attribute__((ext_vector_type(4))) unsigned short u16x4;

// ---------------------------------------------------------------------------
// bf16 helpers
// ---------------------------------------------------------------------------
__device__ inline unsigned short bfbits(float f) {
    __hip_bfloat16 h = __float2bfloat16(f);
    unsigned short u;
    __builtin_memcpy(&u, &h, 2);
    return u;
}
__device__ inline float bf2f(unsigned short u) {
    __hip_bfloat16 h;
    __builtin_memcpy(&h, &u, 2);
    return __bfloat162float(h);
}

__device__ inline void gload_lds16(const unsigned short* g, unsigned short* s) {
    __builtin_amdgcn_global_load_lds(
        (const __attribute__((address_space(1))) unsigned int*)g,
        (__attribute__((address_space(3))) unsigned int*)s, 16, 0, 0);
}

// ---------------------------------------------------------------------------
// Slab adjacency build
// ---------------------------------------------------------------------------
__global__ void slab_fill(const int* __restrict__ ei, int* __restrict__ fill,
                          int* __restrict__ slab) {
    int idx = blockIdx.x * blockDim.x + threadIdx.x;
    if (idx >= ETOT) return;
    int src, dst;
    if (idx < NEDGES) { src = ei[idx]; dst = ei[NEDGES + idx]; }
    else              { src = idx - NEDGES; dst = src; }
    int pos = atomicAdd(&fill[dst], 1);
    if (pos < MAXDEG) slab[dst * MAXDEG + pos] = src;
}

// ---------------------------------------------------------------------------
// Degree binning, contention-free (LDS histograms; 32 global atomics/block).
// ---------------------------------------------------------------------------
__global__ void bin_hist(const int* __restrict__ fill, int* __restrict__ bcnt) {
    __shared__ int h[32];
    const int t = threadIdx.x;
    if (t < 32) h[t] = 0;
    __syncthreads();
    int n = blockIdx.x * 256 + t;
    if (n < NNODES) atomicAdd(&h[min(fill[n], 31)], 1);
    __syncthreads();
    if (t < 32 && h[t] > 0) atomicAdd(&bcnt[t], h[t]);
}

__global__ void bin_scan(const int* __restrict__ bcnt, int* __restrict__ bfill) {
    if (threadIdx.x == 0) {
        int run = 0;
        for (int i = 0; i < 32; i++) { bfill[i] = run; run += bcnt[i]; }
    }
}

__global__ void bin_place(const int* __restrict__ fill, int* __restrict__ bfill,
                          int* __restrict__ order) {
    __shared__ int h[32];
    __shared__ int base[32];
    const int t = threadIdx.x;
    if (t < 32) h[t] = 0;
    __syncthreads();
    int n = blockIdx.x * 256 + t;
    int bin = 0, loc = 0;
    if (n < NNODES) {
        bin = min(fill[n], 31);
        loc = atomicAdd(&h[bin], 1);
    }
    __syncthreads();
    if (t < 32) base[t] = (h[t] > 0) ? atomicAdd(&bfill[t], h[t]) : 0;
    __syncthreads();
    if (n < NNODES) order[base[bin] + loc] = n;
}

// ---------------------------------------------------------------------------
// Split-bf16 conversions (non-temporal writes: consumed cross-XCD only).
// ---------------------------------------------------------------------------
__global__ void convert_x(const float* __restrict__ x, unsigned short* __restrict__ Ap) {
    int idx = blockIdx.x * 256 + threadIdx.x;
    if (idx >= NNODES * 128) return;
    int m = idx >> 7, k = idx & 127;
    float f = x[idx];
    unsigned short hi = bfbits(f);
    unsigned short lo = bfbits(f - bf2f(hi));
    unsigned short* row = Ap + (size_t)m * 256;
    __builtin_nontemporal_store(hi, &row[k]);
    __builtin_nontemporal_store(lo, &row[128 + k]);
}

__global__ void convert_w(const float* __restrict__ w0, const float* __restrict__ w1,
                          unsigned short* __restrict__ Wp, int K, int n0, int ntot) {
    int idx = blockIdx.x * 256 + threadIdx.x;
    if (idx >= ntot * K) return;
    int n = idx / K, k = idx - n * K;
    float f = (n < n0) ? w0[n * K + k] : w1[(n - n0) * K + k];
    unsigned short hi = bfbits(f);
    unsigned short lo = bfbits(f - bf2f(hi));
    unsigned short* row = Wp + (size_t)n * 2 * K;
    row[k] = hi; row[K + k] = lo;
}

// ---------------------------------------------------------------------------
// Split-bf16 MFMA GEMM, 128x128 tile, 4 waves, BK=64, C^T epilogue (float4
// stores) with NON-TEMPORAL OUTPUT STORES: the 40MB O-stream is consumed
// cross-XCD only, so bypassing L2 stops it evicting the W (512KB) and A
// operand tiles -> stage loads become L2 hits instead of ~4TB/s L3 service.
// ---------------------------------------------------------------------------
template <int NOUT>
__global__ __launch_bounds__(256) void gemm_mfma(
    const unsigned short* __restrict__ Ap, int KK,
    const unsigned short* __restrict__ Wp,
    const float* __restrict__ bias0, const float* __restrict__ bias1,
    float* __restrict__ O0, float* __restrict__ O1)
{
    const int W2K = 2 * KK;

    __shared__ unsigned short AH[8192];
    __shared__ unsigned short AL[8192];
    __shared__ unsigned short BH[8192];
    __shared__ unsigned short BL[8192];

    int m0, nblk;
    if constexpr (NOUT == 512) {
        const int bid = blockIdx.x;
        const int xcd = bid & 7;
        const int k   = bid >> 3;
        nblk = k & 3;
        const int g = (k >> 2) * 8 + xcd;
        if (g >= (NNODES + 127) / 128) return;
        m0 = g * 128;
    } else {
        nblk = 0;
        m0 = blockIdx.x * 128;
    }
    const int n0 = nblk * 128;

    const int tid = threadIdx.x;
    const int l   = tid & 63;
    const int wid = tid >> 6;
    const int wr  = wid >> 1;
    const int wc  = wid & 1;

    const int srow = l & 15;
    const int skb  = l >> 4;

    int arow0 = m0 + wid * 16 + srow;
    int arow1 = arow0 + 64;
    arow0 = min(arow0, NNODES - 1);
    arow1 = min(arow1, NNODES - 1);
    const unsigned short* ahg0 = Ap + (size_t)arow0 * W2K + skb * 8;
    const unsigned short* ahg1 = Ap + (size_t)arow1 * W2K + skb * 8;
    int nrow0 = min(n0 + wid * 16 + srow, NOUT - 1);
    int nrow1 = min(n0 + wid * 16 + srow + 64, NOUT - 1);
    const unsigned short* bhg0 = Wp + (size_t)nrow0 * W2K + skb * 8;
    const unsigned short* bhg1 = Wp + (size_t)nrow1 * W2K + skb * 8;

    const int fa0 = (wid * 2) * 512;
    const int fa1 = ((wid + 4) * 2) * 512;

    f32x4 acc[4][4];
    #pragma unroll
    for (int i = 0; i < 4; i++)
        #pragma unroll
        for (int j = 0; j < 4; j++)
            acc[i][j] = (f32x4){0.f, 0.f, 0.f, 0.f};

    const int S = KK >> 6;

    auto STAGE = [&](int k0) {
        #pragma unroll
        for (int c = 0; c < 2; c++) {
            const int ko = k0 + c * 32;
            const int dc = c * 512;
            gload_lds16(ahg0 + ko,      &AH[fa0 + dc]);
            gload_lds16(ahg1 + ko,      &AH[fa1 + dc]);
            gload_lds16(ahg0 + KK + ko, &AL[fa0 + dc]);
            gload_lds16(ahg1 + KK + ko, &AL[fa1 + dc]);
            gload_lds16(bhg0 + ko,      &BH[fa0 + dc]);
            gload_lds16(bhg1 + ko,      &BH[fa1 + dc]);
            gload_lds16(bhg0 + KK + ko, &BL[fa0 + dc]);
            gload_lds16(bhg1 + KK + ko, &BL[fa1 + dc]);
        }
    };

    for (int s = 0; s < S; ++s) {
        STAGE(s * 64);
        __syncthreads();

        #pragma unroll
        for (int c = 0; c < 2; c++) {
            bf16x8 ah[4], al_[4], bh[4], bl[4];
            #pragma unroll
            for (int i = 0; i < 4; i++) {
                const int ra = ((wr * 4 + i) * 2 + c) * 512 + l * 8;
                const int rb = ((wc * 4 + i) * 2 + c) * 512 + l * 8;
                ah[i]  = *(const bf16x8*)&AH[ra];
                al_[i] = *(const bf16x8*)&AL[ra];
                bh[i]  = *(const bf16x8*)&BH[rb];
                bl[i]  = *(const bf16x8*)&BL[rb];
            }
            // swapped operands: D = W_frag x A_frag = C^T
            #pragma unroll
            for (int mi = 0; mi < 4; mi++)
                #pragma unroll
                for (int ni = 0; ni < 4; ni++) {
                    acc[mi][ni] = __builtin_amdgcn_mfma_f32_16x16x32_bf16(bh[ni], ah[mi],  acc[mi][ni], 0, 0, 0);
                    acc[mi][ni] = __builtin_amdgcn_mfma_f32_16x16x32_bf16(bl[ni], ah[mi],  acc[mi][ni], 0, 0, 0);
                    acc[mi][ni] = __builtin_amdgcn_mfma_f32_16x16x32_bf16(bh[ni], al_[mi], acc[mi][ni], 0, 0, 0);
                }
        }

        __syncthreads();
    }

    // epilogue (C^T layout): m = base + (l&15); n = base + (l>>4)*4 + r
    #pragma unroll
    for (int mi = 0; mi < 4; mi++) {
        int m = m0 + wr * 64 + mi * 16 + (l & 15);
        if (m >= NNODES) continue;
        #pragma unroll
        for (int ni = 0; ni < 4; ni++) {
            if constexpr (NOUT == 512) {
                int c = (nblk & 1) * 128 + wc * 64 + ni * 16 + (l >> 4) * 4;
                const bool left = (nblk < 2);
                float*       O  = left ? O0 : O1;
                const float* bs = left ? bias0 : bias1;
                const int head = c >> 6, ch = c & 63;
                f32x4 v = acc[mi][ni];
                v[0] += bs[c + 0];
                v[1] += bs[c + 1];
                v[2] += bs[c + 2];
                v[3] += bs[c + 3];
                __builtin_nontemporal_store(v,
                    (f32x4*)&O[((size_t)head * NNODES + m) * 64 + ch]);
            } else {
                int c = wc * 64 + ni * 16 + (l >> 4) * 4;
                if (c >= 32) continue;
                f32x4 v = acc[mi][ni];
                v[0] += (c + 0 < 16) ? bias0[c + 0] : bias1[c - 16];
                v[1] += (c + 1 < 16) ? bias0[c + 1] : bias1[c + 1 - 16];
                v[2] += (c + 2 < 16) ? bias0[c + 2] : bias1[c + 2 - 16];
                v[3] += (c + 3 < 16) ? bias0[c + 3] : bias1[c + 3 - 16];
                __builtin_nontemporal_store(v, (f32x4*)&O0[(size_t)m * 32 + c]);
            }
        }
    }
}

// ---------------------------------------------------------------------------
// Attention helpers — direct exp (log2e folded into att).
// ---------------------------------------------------------------------------
__device__ inline float edge_score(float4 v, float4 xrv, float4 attv) {
    float tx = v.x + xrv.x; tx = fmaxf(tx, SLOPE * tx);
    float ty = v.y + xrv.y; ty = fmaxf(ty, SLOPE * ty);
    float tz = v.z + xrv.z; tz = fmaxf(tz, SLOPE * tz);
    float tw = v.w + xrv.w; tw = fmaxf(tw, SLOPE * tw);
    float s = attv.x * tx + attv.y * ty + attv.z * tz + attv.w * tw;
    s += __shfl_xor(s, 1, 64);
    s += __shfl_xor(s, 2, 64);
    s += __shfl_xor(s, 4, 64);
    s += __shfl_xor(s, 8, 64);
    return s;
}

// ---------------------------------------------------------------------------
// HEAD-PARTITIONED GATv2 attention (round-15 structure); Ap writes now
// non-temporal (consumed by next GEMM cross-XCD; keeps xl slice in L2).
// ---------------------------------------------------------------------------
__global__ __launch_bounds__(256) void gat_attn_head(
    const float* __restrict__ xl, const float* __restrict__ xr,
    const float* __restrict__ att, const float* __restrict__ bo,
    const int* __restrict__ fill, const int* __restrict__ slab,
    const int* __restrict__ order,
    unsigned short* __restrict__ outp)
{
    const int b    = blockIdx.x;
    const int xcd  = b & 7;
    const int head = xcd >> 1;
    const int wid  = threadIdx.x >> 6;
    const int grp  = ((b >> 3) * 2 + (xcd & 1)) * 4 + wid;
    const int lane = threadIdx.x & 63;
    const int sub  = lane >> 4;
    const int c    = lane & 15;

    const int node = order[grp * 4 + sub];
    const unsigned coff = (unsigned)c << 4;

    const char* xlh = (const char*)xl + (size_t)head * (NNODES * 256);
    const char* xrh = (const char*)xr + (size_t)head * (NNODES * 256);

    float4 attv = *(const float4*)&att[head * 64 + c * 4];
    attv.x *= LOG2E; attv.y *= LOG2E; attv.z *= LOG2E; attv.w *= LOG2E;
    const float4 xrv = *(const float4*)(xrh + ((unsigned)node << 8) + coff);
    const float4 bov = *(const float4*)&bo[head * 64 + c * 4];

    const int  deg = min(fill[node], MAXDEG);
    const int* sl  = slab + node * MAXDEG;

    int maxd = deg;
    maxd = max(maxd, __shfl_xor(maxd, 16, 64));
    maxd = max(maxd, __shfl_xor(maxd, 32, 64));

    float  d0 = 0.f, d1 = 0.f, d2 = 0.f, d3 = 0.f;
    float4 a0 = make_float4(0.f, 0.f, 0.f, 0.f);
    float4 a1 = a0, a2 = a0, a3 = a0;

    auto gather = [&](int src) -> float4 {
        return *(const float4*)(xlh + (((unsigned)src << 8) + coff));
    };

    auto batch = [&](float4 v0, float4 v1, float4 v2, float4 v3, int pb) {
        float s0 = edge_score(v0, xrv, attv);
        float s1 = edge_score(v1, xrv, attv);
        float s2 = edge_score(v2, xrv, attv);
        float s3 = edge_score(v3, xrv, attv);
        float p0 = (pb + 0 < deg) ? exp2f(s0) : 0.f;
        float p1 = (pb + 1 < deg) ? exp2f(s1) : 0.f;
        float p2 = (pb + 2 < deg) ? exp2f(s2) : 0.f;
        float p3 = (pb + 3 < deg) ? exp2f(s3) : 0.f;
        d0 += p0; d1 += p1; d2 += p2; d3 += p3;
        a0.x += p0 * v0.x; a0.y += p0 * v0.y; a0.z += p0 * v0.z; a0.w += p0 * v0.w;
        a1.x += p1 * v1.x; a1.y += p1 * v1.y; a1.z += p1 * v1.z; a1.w += p1 * v1.w;
        a2.x += p2 * v2.x; a2.y += p2 * v2.y; a2.z += p2 * v2.z; a2.w += p2 * v2.w;
        a3.x += p3 * v3.x; a3.y += p3 * v3.y; a3.z += p3 * v3.z; a3.w += p3 * v3.w;
    };

    int4 i0 = *(const int4*)sl;
    float4 v0 = gather((0 < deg) ? i0.x : node);
    float4 v1 = gather((1 < deg) ? i0.y : node);
    float4 v2 = gather((2 < deg) ? i0.z : node);
    float4 v3 = gather((3 < deg) ? i0.w : node);
    int4 i1 = *(const int4*)&sl[4];
    float4 w0 = gather((4 < deg) ? i1.x : node);
    float4 w1 = gather((5 < deg) ? i1.y : node);
    float4 w2 = gather((6 < deg) ? i1.z : node);
    float4 w3 = gather((7 < deg) ? i1.w : node);

    int pv = 0, pw = 4;
    for (int p = 8; p < maxd; p += 4) {
        int4 t4 = *(const int4*)&sl[p];
        float4 u0 = gather((p + 0 < deg) ? t4.x : node);
        float4 u1 = gather((p + 1 < deg) ? t4.y : node);
        float4 u2 = gather((p + 2 < deg) ? t4.z : node);
        float4 u3 = gather((p + 3 < deg) ? t4.w : node);
        batch(v0, v1, v2, v3, pv);
        v0 = w0; v1 = w1; v2 = w2; v3 = w3;
        w0 = u0; w1 = u1; w2 = u2; w3 = u3;
        pv = pw; pw = p;
    }
    batch(v0, v1, v2, v3, pv);
    if (maxd > 4) batch(w0, w1, w2, w3, pw);

    const float den = (d0 + d1) + (d2 + d3);
    float4 o;
    o.x = fmaxf(((a0.x + a1.x) + (a2.x + a3.x)) / den + bov.x, 0.f);
    o.y = fmaxf(((a0.y + a1.y) + (a2.y + a3.y)) / den + bov.y, 0.f);
    o.z = fmaxf(((a0.z + a1.z) + (a2.z + a3.z)) / den + bov.z, 0.f);
    o.w = fmaxf(((a0.w + a1.w) + (a2.w + a3.w)) / den + bov.w, 0.f);

    unsigned short* row = outp + (size_t)node * 512 + head * 64 + c * 4;
    u16x4 hv, lv;
    hv[0] = bfbits(o.x); hv[1] = bfbits(o.y); hv[2] = bfbits(o.z); hv[3] = bfbits(o.w);
    lv[0] = bfbits(o.x - bf2f(hv[0]));
    lv[1] = bfbits(o.y - bf2f(hv[1]));
    lv[2] = bfbits(o.z - bf2f(hv[2]));
    lv[3] = bfbits(o.w - bf2f(hv[3]));
    __builtin_nontemporal_store(hv, (u16x4*)(row));
    __builtin_nontemporal_store(lv, (u16x4*)(row + 256));
}

// ---------------------------------------------------------------------------
// Final layer attention: H=1, OC=16, direct-exp, 4-wave 256-thread blocks.
// ---------------------------------------------------------------------------
__global__ __launch_bounds__(256) void gat_attn_final(
    const float* __restrict__ O32,
    const float* __restrict__ att, const float* __restrict__ bo,
    const int* __restrict__ fill, const int* __restrict__ slab,
    float* __restrict__ out)
{
    const int lane = threadIdx.x & 63;
    const int sub  = lane >> 4;
    const int c    = lane & 15;

    const int node = (blockIdx.x * 4 + (threadIdx.x >> 6)) * 4 + sub;
    if (node >= NNODES) return;

    const unsigned coff = (unsigned)c << 2;
    const char*    ob   = (const char*)O32;

    const float attc = att[c] * LOG2E;
    const float xrc  = *(const float*)(ob + (((unsigned)node << 7) + 64 + coff));

    const int  deg = min(fill[node], MAXDEG);
    const int* sl  = slab + node * MAXDEG;

    float d0 = 0.f, d1 = 0.f, a0 = 0.f, a1 = 0.f;

    int p = 0;
    for (; p + 2 <= deg; p += 2) {
        int srcA = sl[p];
        int srcB = sl[p + 1];
        float vA = *(const float*)(ob + (((unsigned)srcA << 7) + coff));
        float vB = *(const float*)(ob + (((unsigned)srcB << 7) + coff));
        float tA = vA + xrc; tA = fmaxf(tA, SLOPE * tA);
        float tB = vB + xrc; tB = fmaxf(tB, SLOPE * tB);
        float sA = attc * tA;
        float sB = attc * tB;
        sA += __shfl_xor(sA, 1, 64);  sB += __shfl_xor(sB, 1, 64);
        sA += __shfl_xor(sA, 2, 64);  sB += __shfl_xor(sB, 2, 64);
        sA += __shfl_xor(sA, 4, 64);  sB += __shfl_xor(sB, 4, 64);
        sA += __shfl_xor(sA, 8, 64);  sB += __shfl_xor(sB, 8, 64);
        float pA = exp2f(sA);
        float pB = exp2f(sB);
        d0 += pA; a0 += pA * vA;
        d1 += pB; a1 += pB * vB;
    }
    if (p < deg) {
        int src = sl[p];
        float v = *(const float*)(ob + (((unsigned)src << 7) + coff));
        float t = v + xrc; t = fmaxf(t, SLOPE * t);
        float s = attc * t;
        s += __shfl_xor(s, 1, 64);
        s += __shfl_xor(s, 2, 64);
        s += __shfl_xor(s, 4, 64);
        s += __shfl_xor(s, 8, 64);
        float pw = exp2f(s);
        d0 += pw; a0 += pw * v;
    }

    out[(size_t)node * 16 + c] = (a0 + a1) / (d0 + d1) + bo[c];
}

// ---------------------------------------------------------------------------
extern "C" void kernel_launch(void* const* d_in, const int* in_sizes, int n_in,
                              void* d_out, int out_size, void* d_ws, size_t ws_size,
                              hipStream_t stream)
{
    const float* x   = (const float*)d_in[0];
    const int*   ei  = (const int*)d_in[1];
    const float* w1l = (const float*)d_in[2];  const float* b1l = (const float*)d_in[3];
    const float* w1r = (const float*)d_in[4];  const float* b1r = (const float*)d_in[5];
    const float* a1  = (const float*)d_in[6];  const float* bo1 = (const float*)d_in[7];
    const float* w2l = (const float*)d_in[8];  const float* b2l = (const float*)d_in[9];
    const float* w2r = (const float*)d_in[10]; const float* b2r = (const float*)d_in[11];
    const float* a2  = (const float*)d_in[12]; const float* bo2 = (const float*)d_in[13];
    const float* w3l = (const float*)d_in[14]; const float* b3l = (const float*)d_in[15];
    const float* w3r = (const float*)d_in[16]; const float* b3r = (const float*)d_in[17];
    const float* a3  = (const float*)d_in[18]; const float* bo3 = (const float*)d_in[19];
    const float* w4l = (const float*)d_in[20]; const float* b4l = (const float*)d_in[21];
    const float* w4r = (const float*)d_in[22]; const float* b4r = (const float*)d_in[23];
    const float* a4  = (const float*)d_in[24]; const float* bo4 = (const float*)d_in[25];

    char* ws = (char*)d_ws;
    auto carve = [&](size_t bytes) {
        void* p = ws;
        ws += (bytes + 255) & ~(size_t)255;
        return p;
    };
    unsigned short* Ap = (unsigned short*)carve((size_t)NNODES * 512 * sizeof(unsigned short));
    float* xl = (float*)carve((size_t)NNODES * 256 * sizeof(float));   // head-major [4][N][64]
    float* xr = (float*)carve((size_t)NNODES * 256 * sizeof(float));   // head-major
    float* O32 = xl;   // layer-4 output reuses xl (free after attn3)
    unsigned short* Wp1 = (unsigned short*)carve((size_t)512 * 256 * sizeof(unsigned short));
    unsigned short* Wp2 = (unsigned short*)carve((size_t)512 * 512 * sizeof(unsigned short));
    unsigned short* Wp3 = (unsigned short*)carve((size_t)512 * 512 * sizeof(unsigned short));
    unsigned short* Wp4 = (unsigned short*)carve((size_t)32 * 512 * sizeof(unsigned short));
    int* fill  = (int*)carve((size_t)NNODES * sizeof(int));
    int* slab  = (int*)carve((size_t)NNODES * MAXDEG * sizeof(int));
    int* bcnt  = (int*)carve(32 * sizeof(int));
    int* bfill = (int*)carve(32 * sizeof(int));
    int* order = (int*)carve((size_t)NNODES * sizeof(int));

    const int eblocks = (ETOT + 255) / 256;
    const int nblocks = (NNODES + 255) / 256;

    // ---- conversions ----
    convert_x<<<(NNODES * 128 + 255) / 256, 256, 0, stream>>>(x, Ap);
    convert_w<<<(512 * 128 + 255) / 256, 256, 0, stream>>>(w1l, w1r, Wp1, 128, 256, 512);
    convert_w<<<(512 * 256 + 255) / 256, 256, 0, stream>>>(w2l, w2r, Wp2, 256, 256, 512);
    convert_w<<<(512 * 256 + 255) / 256, 256, 0, stream>>>(w3l, w3r, Wp3, 256, 256, 512);
    convert_w<<<(32 * 256 + 255) / 256, 256, 0, stream>>>(w4l, w4r, Wp4, 256, 16, 32);

    // ---- adjacency slab + degree binning (contention-free) ----
    hipMemsetAsync(fill, 0, (size_t)NNODES * sizeof(int), stream);
    hipMemsetAsync(bcnt, 0, 32 * sizeof(int), stream);
    slab_fill<<<eblocks, 256, 0, stream>>>(ei, fill, slab);
    bin_hist<<<nblocks, 256, 0, stream>>>(fill, bcnt);
    bin_scan<<<1, 64, 0, stream>>>(bcnt, bfill);
    bin_place<<<nblocks, 256, 0, stream>>>(fill, bfill, order);

    const int g512 = 640;                    // 8 xcd x 4 nblk x 20 m-groups
    const int g32  = (NNODES + 127) / 128;   // 157
    const int ah   = 5000;                   // attn: 4-wave blocks, XCD-pinned

    // ---- Layer 1 (K=128) ----
    gemm_mfma<512><<<g512, 256, 0, stream>>>(Ap, 128, Wp1, b1l, b1r, xl, xr);
    gat_attn_head<<<ah, 256, 0, stream>>>(xl, xr, a1, bo1, fill, slab, order, Ap);

    // ---- Layer 2 (K=256) ----
    gemm_mfma<512><<<g512, 256, 0, stream>>>(Ap, 256, Wp2, b2l, b2r, xl, xr);
    gat_attn_head<<<ah, 256, 0, stream>>>(xl, xr, a2, bo2, fill, slab, order, Ap);

    // ---- Layer 3 (K=256) ----
    gemm_mfma<512><<<g512, 256, 0, stream>>>(Ap, 256, Wp3, b3l, b3r, xl, xr);
    gat_attn_head<<<ah, 256, 0, stream>>>(xl, xr, a3, bo3, fill, slab, order, Ap);

    // ---- Layer 4 (K=256, NOUT=32) ----
    gemm_mfma<32><<<g32, 256, 0, stream>>>(Ap, 256, Wp4, b4l, b4r, O32, O32);
    gat_attn_final<<<(NNODES + 15) / 16, 256, 0, stream>>>(O32, a4, bo4, fill, slab, (float*)d_out);
}

// Round 20
// 277.115 us; speedup vs baseline: 1.0591x; 1.0591x over previous
//
#include <hip/hip_runtime.h>
#include <hip/hip_bf16.h>
#include <math.h>

#define NNODES 20000
#define NEDGES 320000
#define ETOT   (NEDGES + NNODES)
#define SLOPE  0.2f
#define MAXDEG 96
#define LOG2E  1.44269504088896f

typedef __attribute__((ext_vector_type(8))) short bf16x8;
typedef __attribute__((ext_vector_type(4))) float f32x4;

// ---------------------------------------------------------------------------
// bf16 helpers
// ---------------------------------------------------------------------------
__device__ inline unsigned short bfbits(float f) {
    __hip_bfloat16 h = __float2bfloat16(f);
    unsigned short u;
    __builtin_memcpy(&u, &h, 2);
    return u;
}
__device__ inline float bf2f(unsigned short u) {
    __hip_bfloat16 h;
    __builtin_memcpy(&h, &u, 2);
    return __bfloat162float(h);
}

__device__ inline void gload_lds16(const unsigned short* g, unsigned short* s) {
    __builtin_amdgcn_global_load_lds(
        (const __attribute__((address_space(1))) unsigned int*)g,
        (__attribute__((address_space(3))) unsigned int*)s, 16, 0, 0);
}

// ---------------------------------------------------------------------------
// Slab adjacency build
// ---------------------------------------------------------------------------
__global__ void slab_fill(const int* __restrict__ ei, int* __restrict__ fill,
                          int* __restrict__ slab) {
    int idx = blockIdx.x * blockDim.x + threadIdx.x;
    if (idx >= ETOT) return;
    int src, dst;
    if (idx < NEDGES) { src = ei[idx]; dst = ei[NEDGES + idx]; }
    else              { src = idx - NEDGES; dst = src; }
    int pos = atomicAdd(&fill[dst], 1);
    if (pos < MAXDEG) slab[dst * MAXDEG + pos] = src;
}

// ---------------------------------------------------------------------------
// Degree binning, contention-free (LDS histograms; 32 global atomics/block).
// ---------------------------------------------------------------------------
__global__ void bin_hist(const int* __restrict__ fill, int* __restrict__ bcnt) {
    __shared__ int h[32];
    const int t = threadIdx.x;
    if (t < 32) h[t] = 0;
    __syncthreads();
    int n = blockIdx.x * 256 + t;
    if (n < NNODES) atomicAdd(&h[min(fill[n], 31)], 1);
    __syncthreads();
    if (t < 32 && h[t] > 0) atomicAdd(&bcnt[t], h[t]);
}

__global__ void bin_scan(const int* __restrict__ bcnt, int* __restrict__ bfill) {
    if (threadIdx.x == 0) {
        int run = 0;
        for (int i = 0; i < 32; i++) { bfill[i] = run; run += bcnt[i]; }
    }
}

__global__ void bin_place(const int* __restrict__ fill, int* __restrict__ bfill,
                          int* __restrict__ order) {
    __shared__ int h[32];
    __shared__ int base[32];
    const int t = threadIdx.x;
    if (t < 32) h[t] = 0;
    __syncthreads();
    int n = blockIdx.x * 256 + t;
    int bin = 0, loc = 0;
    if (n < NNODES) {
        bin = min(fill[n], 31);
        loc = atomicAdd(&h[bin], 1);
    }
    __syncthreads();
    if (t < 32) base[t] = (h[t] > 0) ? atomicAdd(&bfill[t], h[t]) : 0;
    __syncthreads();
    if (n < NNODES) order[base[bin] + loc] = n;
}

// ---------------------------------------------------------------------------
// Split-bf16 conversions. A'' = [Ah | Al] (width 2K); W'' = [Wh | Wl].
// ---------------------------------------------------------------------------
__global__ void convert_x(const float* __restrict__ x, unsigned short* __restrict__ Ap) {
    int idx = blockIdx.x * 256 + threadIdx.x;
    if (idx >= NNODES * 128) return;
    int m = idx >> 7, k = idx & 127;
    float f = x[idx];
    unsigned short hi = bfbits(f);
    unsigned short lo = bfbits(f - bf2f(hi));
    unsigned short* row = Ap + (size_t)m * 256;
    row[k] = hi; row[128 + k] = lo;
}

__global__ void convert_w(const float* __restrict__ w0, const float* __restrict__ w1,
                          unsigned short* __restrict__ Wp, int K, int n0, int ntot) {
    int idx = blockIdx.x * 256 + threadIdx.x;
    if (idx >= ntot * K) return;
    int n = idx / K, k = idx - n * K;
    float f = (n < n0) ? w0[n * K + k] : w1[(n - n0) * K + k];
    unsigned short hi = bfbits(f);
    unsigned short lo = bfbits(f - bf2f(hi));
    unsigned short* row = Wp + (size_t)n * 2 * K;
    row[k] = hi; row[K + k] = lo;
}

// ---------------------------------------------------------------------------
// Split-bf16 MFMA GEMM, 128x128 tile, 4 waves, BK=64, SWAPPED MFMA OPERANDS:
// acc = mfma(W_frag, A_frag) computes C^T, lane layout m = l&15,
// n = (l>>4)*4 + reg -> each lane holds 4 consecutive output columns of one
// row. Epilogue: 16 float4 stores/thread (regular stores; NT variant
// regressed by defeating L2 write-combining — round 19).
// ---------------------------------------------------------------------------
template <int NOUT>
__global__ __launch_bounds__(256) void gemm_mfma(
    const unsigned short* __restrict__ Ap, int KK,
    const unsigned short* __restrict__ Wp,
    const float* __restrict__ bias0, const float* __restrict__ bias1,
    float* __restrict__ O0, float* __restrict__ O1)
{
    const int W2K = 2 * KK;

    __shared__ unsigned short AH[8192];   // 8 frags x 2 chunks x 512
    __shared__ unsigned short AL[8192];
    __shared__ unsigned short BH[8192];
    __shared__ unsigned short BL[8192];

    int m0, nblk;
    if constexpr (NOUT == 512) {
        const int bid = blockIdx.x;
        const int xcd = bid & 7;
        const int k   = bid >> 3;
        nblk = k & 3;
        const int g = (k >> 2) * 8 + xcd;
        if (g >= (NNODES + 127) / 128) return;
        m0 = g * 128;
    } else {
        nblk = 0;
        m0 = blockIdx.x * 128;
    }
    const int n0 = nblk * 128;

    const int tid = threadIdx.x;
    const int l   = tid & 63;
    const int wid = tid >> 6;
    const int wr  = wid >> 1;
    const int wc  = wid & 1;

    const int srow = l & 15;
    const int skb  = l >> 4;

    int arow0 = m0 + wid * 16 + srow;
    int arow1 = arow0 + 64;
    arow0 = min(arow0, NNODES - 1);
    arow1 = min(arow1, NNODES - 1);
    const unsigned short* ahg0 = Ap + (size_t)arow0 * W2K + skb * 8;
    const unsigned short* ahg1 = Ap + (size_t)arow1 * W2K + skb * 8;
    int nrow0 = min(n0 + wid * 16 + srow, NOUT - 1);
    int nrow1 = min(n0 + wid * 16 + srow + 64, NOUT - 1);
    const unsigned short* bhg0 = Wp + (size_t)nrow0 * W2K + skb * 8;
    const unsigned short* bhg1 = Wp + (size_t)nrow1 * W2K + skb * 8;

    const int fa0 = (wid * 2) * 512;
    const int fa1 = ((wid + 4) * 2) * 512;

    f32x4 acc[4][4];
    #pragma unroll
    for (int i = 0; i < 4; i++)
        #pragma unroll
        for (int j = 0; j < 4; j++)
            acc[i][j] = (f32x4){0.f, 0.f, 0.f, 0.f};

    const int S = KK >> 6;

    auto STAGE = [&](int k0) {
        #pragma unroll
        for (int c = 0; c < 2; c++) {
            const int ko = k0 + c * 32;
            const int dc = c * 512;
            gload_lds16(ahg0 + ko,      &AH[fa0 + dc]);
            gload_lds16(ahg1 + ko,      &AH[fa1 + dc]);
            gload_lds16(ahg0 + KK + ko, &AL[fa0 + dc]);
            gload_lds16(ahg1 + KK + ko, &AL[fa1 + dc]);
            gload_lds16(bhg0 + ko,      &BH[fa0 + dc]);
            gload_lds16(bhg1 + ko,      &BH[fa1 + dc]);
            gload_lds16(bhg0 + KK + ko, &BL[fa0 + dc]);
            gload_lds16(bhg1 + KK + ko, &BL[fa1 + dc]);
        }
    };

    for (int s = 0; s < S; ++s) {
        STAGE(s * 64);
        __syncthreads();

        #pragma unroll
        for (int c = 0; c < 2; c++) {
            bf16x8 ah[4], al_[4], bh[4], bl[4];
            #pragma unroll
            for (int i = 0; i < 4; i++) {
                const int ra = ((wr * 4 + i) * 2 + c) * 512 + l * 8;
                const int rb = ((wc * 4 + i) * 2 + c) * 512 + l * 8;
                ah[i]  = *(const bf16x8*)&AH[ra];
                al_[i] = *(const bf16x8*)&AL[ra];
                bh[i]  = *(const bf16x8*)&BH[rb];
                bl[i]  = *(const bf16x8*)&BL[rb];
            }
            // swapped operands: D = W_frag x A_frag = C^T
            #pragma unroll
            for (int mi = 0; mi < 4; mi++)
                #pragma unroll
                for (int ni = 0; ni < 4; ni++) {
                    acc[mi][ni] = __builtin_amdgcn_mfma_f32_16x16x32_bf16(bh[ni], ah[mi],  acc[mi][ni], 0, 0, 0);
                    acc[mi][ni] = __builtin_amdgcn_mfma_f32_16x16x32_bf16(bl[ni], ah[mi],  acc[mi][ni], 0, 0, 0);
                    acc[mi][ni] = __builtin_amdgcn_mfma_f32_16x16x32_bf16(bh[ni], al_[mi], acc[mi][ni], 0, 0, 0);
                }
        }

        __syncthreads();
    }

    // epilogue (C^T layout): m = frag_m_base + (l&15); n = frag_n_base +
    // (l>>4)*4 + r  -> one float4 store per (mi,ni).
    #pragma unroll
    for (int mi = 0; mi < 4; mi++) {
        int m = m0 + wr * 64 + mi * 16 + (l & 15);
        if (m >= NNODES) continue;
        #pragma unroll
        for (int ni = 0; ni < 4; ni++) {
            if constexpr (NOUT == 512) {
                int c = (nblk & 1) * 128 + wc * 64 + ni * 16 + (l >> 4) * 4;
                const bool left = (nblk < 2);
                float*       O  = left ? O0 : O1;
                const float* bs = left ? bias0 : bias1;
                const int head = c >> 6, ch = c & 63;   // uniform head per frag
                float4 v;
                v.x = acc[mi][ni][0] + bs[c + 0];
                v.y = acc[mi][ni][1] + bs[c + 1];
                v.z = acc[mi][ni][2] + bs[c + 2];
                v.w = acc[mi][ni][3] + bs[c + 3];
                *(float4*)&O[((size_t)head * NNODES + m) * 64 + ch] = v;
            } else {
                int c = wc * 64 + ni * 16 + (l >> 4) * 4;
                if (c >= 32) continue;
                float4 v;
                v.x = acc[mi][ni][0] + ((c + 0 < 16) ? bias0[c + 0] : bias1[c - 16]);
                v.y = acc[mi][ni][1] + ((c + 1 < 16) ? bias0[c + 1] : bias1[c + 1 - 16]);
                v.z = acc[mi][ni][2] + ((c + 2 < 16) ? bias0[c + 2] : bias1[c + 2 - 16]);
                v.w = acc[mi][ni][3] + ((c + 3 < 16) ? bias0[c + 3] : bias1[c + 3 - 16]);
                *(float4*)&O0[(size_t)m * 32 + c] = v;
            }
        }
    }
}

// ---------------------------------------------------------------------------
// Attention helpers — direct exp (log2e folded into att).
// ---------------------------------------------------------------------------
__device__ inline float edge_score(float4 v, float4 xrv, float4 attv) {
    float tx = v.x + xrv.x; tx = fmaxf(tx, SLOPE * tx);
    float ty = v.y + xrv.y; ty = fmaxf(ty, SLOPE * ty);
    float tz = v.z + xrv.z; tz = fmaxf(tz, SLOPE * tz);
    float tw = v.w + xrv.w; tw = fmaxf(tw, SLOPE * tw);
    float s = attv.x * tx + attv.y * ty + attv.z * tz + attv.w * tw;
    s += __shfl_xor(s, 1, 64);
    s += __shfl_xor(s, 2, 64);
    s += __shfl_xor(s, 4, 64);
    s += __shfl_xor(s, 8, 64);
    return s;
}

// ---------------------------------------------------------------------------
// HEAD-PARTITIONED GATv2 attention (round-15 structure, regular stores).
// ---------------------------------------------------------------------------
__global__ __launch_bounds__(256) void gat_attn_head(
    const float* __restrict__ xl, const float* __restrict__ xr,
    const float* __restrict__ att, const float* __restrict__ bo,
    const int* __restrict__ fill, const int* __restrict__ slab,
    const int* __restrict__ order,
    unsigned short* __restrict__ outp)
{
    const int b    = blockIdx.x;
    const int xcd  = b & 7;
    const int head = xcd >> 1;
    const int wid  = threadIdx.x >> 6;
    const int grp  = ((b >> 3) * 2 + (xcd & 1)) * 4 + wid;
    const int lane = threadIdx.x & 63;
    const int sub  = lane >> 4;
    const int c    = lane & 15;

    const int node = order[grp * 4 + sub];
    const unsigned coff = (unsigned)c << 4;

    const char* xlh = (const char*)xl + (size_t)head * (NNODES * 256);
    const char* xrh = (const char*)xr + (size_t)head * (NNODES * 256);

    float4 attv = *(const float4*)&att[head * 64 + c * 4];
    attv.x *= LOG2E; attv.y *= LOG2E; attv.z *= LOG2E; attv.w *= LOG2E;
    const float4 xrv = *(const float4*)(xrh + ((unsigned)node << 8) + coff);
    const float4 bov = *(const float4*)&bo[head * 64 + c * 4];

    const int  deg = min(fill[node], MAXDEG);
    const int* sl  = slab + node * MAXDEG;

    int maxd = deg;
    maxd = max(maxd, __shfl_xor(maxd, 16, 64));
    maxd = max(maxd, __shfl_xor(maxd, 32, 64));

    float  d0 = 0.f, d1 = 0.f, d2 = 0.f, d3 = 0.f;
    float4 a0 = make_float4(0.f, 0.f, 0.f, 0.f);
    float4 a1 = a0, a2 = a0, a3 = a0;

    auto gather = [&](int src) -> float4 {
        return *(const float4*)(xlh + (((unsigned)src << 8) + coff));
    };

    auto batch = [&](float4 v0, float4 v1, float4 v2, float4 v3, int pb) {
        float s0 = edge_score(v0, xrv, attv);
        float s1 = edge_score(v1, xrv, attv);
        float s2 = edge_score(v2, xrv, attv);
        float s3 = edge_score(v3, xrv, attv);
        float p0 = (pb + 0 < deg) ? exp2f(s0) : 0.f;
        float p1 = (pb + 1 < deg) ? exp2f(s1) : 0.f;
        float p2 = (pb + 2 < deg) ? exp2f(s2) : 0.f;
        float p3 = (pb + 3 < deg) ? exp2f(s3) : 0.f;
        d0 += p0; d1 += p1; d2 += p2; d3 += p3;
        a0.x += p0 * v0.x; a0.y += p0 * v0.y; a0.z += p0 * v0.z; a0.w += p0 * v0.w;
        a1.x += p1 * v1.x; a1.y += p1 * v1.y; a1.z += p1 * v1.z; a1.w += p1 * v1.w;
        a2.x += p2 * v2.x; a2.y += p2 * v2.y; a2.z += p2 * v2.z; a2.w += p2 * v2.w;
        a3.x += p3 * v3.x; a3.y += p3 * v3.y; a3.z += p3 * v3.z; a3.w += p3 * v3.w;
    };

    int4 i0 = *(const int4*)sl;
    float4 v0 = gather((0 < deg) ? i0.x : node);
    float4 v1 = gather((1 < deg) ? i0.y : node);
    float4 v2 = gather((2 < deg) ? i0.z : node);
    float4 v3 = gather((3 < deg) ? i0.w : node);
    int4 i1 = *(const int4*)&sl[4];
    float4 w0 = gather((4 < deg) ? i1.x : node);
    float4 w1 = gather((5 < deg) ? i1.y : node);
    float4 w2 = gather((6 < deg) ? i1.z : node);
    float4 w3 = gather((7 < deg) ? i1.w : node);

    int pv = 0, pw = 4;
    for (int p = 8; p < maxd; p += 4) {
        int4 t4 = *(const int4*)&sl[p];
        float4 u0 = gather((p + 0 < deg) ? t4.x : node);
        float4 u1 = gather((p + 1 < deg) ? t4.y : node);
        float4 u2 = gather((p + 2 < deg) ? t4.z : node);
        float4 u3 = gather((p + 3 < deg) ? t4.w : node);
        batch(v0, v1, v2, v3, pv);
        v0 = w0; v1 = w1; v2 = w2; v3 = w3;
        w0 = u0; w1 = u1; w2 = u2; w3 = u3;
        pv = pw; pw = p;
    }
    batch(v0, v1, v2, v3, pv);
    if (maxd > 4) batch(w0, w1, w2, w3, pw);

    const float den = (d0 + d1) + (d2 + d3);
    float4 o;
    o.x = fmaxf(((a0.x + a1.x) + (a2.x + a3.x)) / den + bov.x, 0.f);
    o.y = fmaxf(((a0.y + a1.y) + (a2.y + a3.y)) / den + bov.y, 0.f);
    o.z = fmaxf(((a0.z + a1.z) + (a2.z + a3.z)) / den + bov.z, 0.f);
    o.w = fmaxf(((a0.w + a1.w) + (a2.w + a3.w)) / den + bov.w, 0.f);

    unsigned short* row = outp + (size_t)node * 512 + head * 64 + c * 4;
    ushort4 hv, lv;
    hv.x = bfbits(o.x); hv.y = bfbits(o.y); hv.z = bfbits(o.z); hv.w = bfbits(o.w);
    lv.x = bfbits(o.x - bf2f(hv.x));
    lv.y = bfbits(o.y - bf2f(hv.y));
    lv.z = bfbits(o.z - bf2f(hv.z));
    lv.w = bfbits(o.w - bf2f(hv.w));
    *(ushort4*)(row)       = hv;
    *(ushort4*)(row + 256) = lv;
}

// ---------------------------------------------------------------------------
// Final layer attention: H=1, OC=16, direct-exp, 4-wave 256-thread blocks.
// ---------------------------------------------------------------------------
__global__ __launch_bounds__(256) void gat_attn_final(
    const float* __restrict__ O32,
    const float* __restrict__ att, const float* __restrict__ bo,
    const int* __restrict__ fill, const int* __restrict__ slab,
    float* __restrict__ out)
{
    const int lane = threadIdx.x & 63;
    const int sub  = lane >> 4;
    const int c    = lane & 15;

    const int node = (blockIdx.x * 4 + (threadIdx.x >> 6)) * 4 + sub;
    if (node >= NNODES) return;

    const unsigned coff = (unsigned)c << 2;
    const char*    ob   = (const char*)O32;

    const float attc = att[c] * LOG2E;
    const float xrc  = *(const float*)(ob + (((unsigned)node << 7) + 64 + coff));

    const int  deg = min(fill[node], MAXDEG);
    const int* sl  = slab + node * MAXDEG;

    float d0 = 0.f, d1 = 0.f, a0 = 0.f, a1 = 0.f;

    int p = 0;
    for (; p + 2 <= deg; p += 2) {
        int srcA = sl[p];
        int srcB = sl[p + 1];
        float vA = *(const float*)(ob + (((unsigned)srcA << 7) + coff));
        float vB = *(const float*)(ob + (((unsigned)srcB << 7) + coff));
        float tA = vA + xrc; tA = fmaxf(tA, SLOPE * tA);
        float tB = vB + xrc; tB = fmaxf(tB, SLOPE * tB);
        float sA = attc * tA;
        float sB = attc * tB;
        sA += __shfl_xor(sA, 1, 64);  sB += __shfl_xor(sB, 1, 64);
        sA += __shfl_xor(sA, 2, 64);  sB += __shfl_xor(sB, 2, 64);
        sA += __shfl_xor(sA, 4, 64);  sB += __shfl_xor(sB, 4, 64);
        sA += __shfl_xor(sA, 8, 64);  sB += __shfl_xor(sB, 8, 64);
        float pA = exp2f(sA);
        float pB = exp2f(sB);
        d0 += pA; a0 += pA * vA;
        d1 += pB; a1 += pB * vB;
    }
    if (p < deg) {
        int src = sl[p];
        float v = *(const float*)(ob + (((unsigned)src << 7) + coff));
        float t = v + xrc; t = fmaxf(t, SLOPE * t);
        float s = attc * t;
        s += __shfl_xor(s, 1, 64);
        s += __shfl_xor(s, 2, 64);
        s += __shfl_xor(s, 4, 64);
        s += __shfl_xor(s, 8, 64);
        float pw = exp2f(s);
        d0 += pw; a0 += pw * v;
    }

    out[(size_t)node * 16 + c] = (a0 + a1) / (d0 + d1) + bo[c];
}

// ---------------------------------------------------------------------------
extern "C" void kernel_launch(void* const* d_in, const int* in_sizes, int n_in,
                              void* d_out, int out_size, void* d_ws, size_t ws_size,
                              hipStream_t stream)
{
    const float* x   = (const float*)d_in[0];
    const int*   ei  = (const int*)d_in[1];
    const float* w1l = (const float*)d_in[2];  const float* b1l = (const float*)d_in[3];
    const float* w1r = (const float*)d_in[4];  const float* b1r = (const float*)d_in[5];
    const float* a1  = (const float*)d_in[6];  const float* bo1 = (const float*)d_in[7];
    const float* w2l = (const float*)d_in[8];  const float* b2l = (const float*)d_in[9];
    const float* w2r = (const float*)d_in[10]; const float* b2r = (const float*)d_in[11];
    const float* a2  = (const float*)d_in[12]; const float* bo2 = (const float*)d_in[13];
    const float* w3l = (const float*)d_in[14]; const float* b3l = (const float*)d_in[15];
    const float* w3r = (const float*)d_in[16]; const float* b3r = (const float*)d_in[17];
    const float* a3  = (const float*)d_in[18]; const float* bo3 = (const float*)d_in[19];
    const float* w4l = (const float*)d_in[20]; const float* b4l = (const float*)d_in[21];
    const float* w4r = (const float*)d_in[22]; const float* b4r = (const float*)d_in[23];
    const float* a4  = (const float*)d_in[24]; const float* bo4 = (const float*)d_in[25];

    char* ws = (char*)d_ws;
    auto carve = [&](size_t bytes) {
        void* p = ws;
        ws += (bytes + 255) & ~(size_t)255;
        return p;
    };
    unsigned short* Ap = (unsigned short*)carve((size_t)NNODES * 512 * sizeof(unsigned short));
    float* xl = (float*)carve((size_t)NNODES * 256 * sizeof(float));   // head-major [4][N][64]
    float* xr = (float*)carve((size_t)NNODES * 256 * sizeof(float));   // head-major
    float* O32 = xl;   // layer-4 output reuses xl (free after attn3)
    unsigned short* Wp1 = (unsigned short*)carve((size_t)512 * 256 * sizeof(unsigned short));
    unsigned short* Wp2 = (unsigned short*)carve((size_t)512 * 512 * sizeof(unsigned short));
    unsigned short* Wp3 = (unsigned short*)carve((size_t)512 * 512 * sizeof(unsigned short));
    unsigned short* Wp4 = (unsigned short*)carve((size_t)32 * 512 * sizeof(unsigned short));
    int* fill  = (int*)carve((size_t)NNODES * sizeof(int));
    int* slab  = (int*)carve((size_t)NNODES * MAXDEG * sizeof(int));
    int* bcnt  = (int*)carve(32 * sizeof(int));
    int* bfill = (int*)carve(32 * sizeof(int));
    int* order = (int*)carve((size_t)NNODES * sizeof(int));

    const int eblocks = (ETOT + 255) / 256;
    const int nblocks = (NNODES + 255) / 256;

    // ---- conversions ----
    convert_x<<<(NNODES * 128 + 255) / 256, 256, 0, stream>>>(x, Ap);
    convert_w<<<(512 * 128 + 255) / 256, 256, 0, stream>>>(w1l, w1r, Wp1, 128, 256, 512);
    convert_w<<<(512 * 256 + 255) / 256, 256, 0, stream>>>(w2l, w2r, Wp2, 256, 256, 512);
    convert_w<<<(512 * 256 + 255) / 256, 256, 0, stream>>>(w3l, w3r, Wp3, 256, 256, 512);
    convert_w<<<(32 * 256 + 255) / 256, 256, 0, stream>>>(w4l, w4r, Wp4, 256, 16, 32);

    // ---- adjacency slab + degree binning (contention-free) ----
    hipMemsetAsync(fill, 0, (size_t)NNODES * sizeof(int), stream);
    hipMemsetAsync(bcnt, 0, 32 * sizeof(int), stream);
    slab_fill<<<eblocks, 256, 0, stream>>>(ei, fill, slab);
    bin_hist<<<nblocks, 256, 0, stream>>>(fill, bcnt);
    bin_scan<<<1, 64, 0, stream>>>(bcnt, bfill);
    bin_place<<<nblocks, 256, 0, stream>>>(fill, bfill, order);

    const int g512 = 640;                    // 8 xcd x 4 nblk x 20 m-groups
    const int g32  = (NNODES + 127) / 128;   // 157
    const int ah   = 5000;                   // attn: 4-wave blocks, XCD-pinned

    // ---- Layer 1 (K=128) ----
    gemm_mfma<512><<<g512, 256, 0, stream>>>(Ap, 128, Wp1, b1l, b1r, xl, xr);
    gat_attn_head<<<ah, 256, 0, stream>>>(xl, xr, a1, bo1, fill, slab, order, Ap);

    // ---- Layer 2 (K=256) ----
    gemm_mfma<512><<<g512, 256, 0, stream>>>(Ap, 256, Wp2, b2l, b2r, xl, xr);
    gat_attn_head<<<ah, 256, 0, stream>>>(xl, xr, a2, bo2, fill, slab, order, Ap);

    // ---- Layer 3 (K=256) ----
    gemm_mfma<512><<<g512, 256, 0, stream>>>(Ap, 256, Wp3, b3l, b3r, xl, xr);
    gat_attn_head<<<ah, 256, 0, stream>>>(xl, xr, a3, bo3, fill, slab, order, Ap);

    // ---- Layer 4 (K=256, NOUT=32) ----
    gemm_mfma<32><<<g32, 256, 0, stream>>>(Ap, 256, Wp4, b4l, b4r, O32, O32);
    gat_attn_final<<<(NNODES + 15) / 16, 256, 0, stream>>>(O32, a4, bo4, fill, slab, (float*)d_out);
}